// Round 13
// baseline (225.973 us; speedup 1.0000x reference)
//
#include <hip/hip_runtime.h>
#include <math.h>

// RBF mixture: out[i] = sum_m w_m * exp(-(x_i-mu_m)^T C_m (x_i-mu_m)), C_m = G_m G_m^T
// N=32768, M=2048, D=32.
// Round 29: resubmit of r28 (round-12 bench was an infra failure, no signal).
//  - screen: ROWS=64 (73.7KB LDS -> 2 blocks/CU = 4 waves/SIMD), acc[4][4],
//    2-deep B rotation, amdgpu_waves_per_eu(4,4) pins 128-unified budget
//    (r21 proved this shape spill-free). Coalesced fragment-major B (r26).
//  - SCREEN=104 (r27-verified margin), other kernels verbatim.
// 4 dispatches total.

#define NN 32768
#define MM 2048
#define DDIM 32
#define KSYM 576           // 528 triangle + 32 cross + 2 const + 14 pad = 18*32
#define ROWS 64
#define KSTEPS 18
#define SCREEN 104.0f
#define MCAP 2048
#define FCAP 1000000
#define FBLK 64
#define GRPHW 9216         // halfwords per 16-m B group: 16*576

typedef __attribute__((ext_vector_type(8))) short short8;
typedef __attribute__((ext_vector_type(4))) float floatx4;

__device__ __forceinline__ unsigned int to_bf16(float f) {
  union { float f; unsigned int u; } x; x.f = f;
  return (x.u + 0x7fffu + ((x.u >> 16) & 1u)) >> 16;   // RNE, finite inputs only
}

struct DFTab { unsigned char d[528]; unsigned char f[528]; };
constexpr DFTab make_df() {
  DFTab t{};
  int s = 0;
  for (int d = 0; d < 32; ++d)
    for (int f = d; f < 32; ++f) {
      t.d[s] = (unsigned char)d; t.f[s] = (unsigned char)f; ++s;
    }
  return t;
}
constexpr DFTab DFT = make_df();

__device__ __forceinline__ float slot_val(const float* v, int s) {
  if (s < 528) return v[DFT.d[s]] * v[DFT.f[s]];
  if (s < 560) return v[s - 528];
  if (s < 562) return 1.f;
  return 0.f;
}

__device__ __forceinline__ void slot_df(int s, int* dd, int* ff) {
  int d = 0, b = 0;
  while (b + (DDIM - d) <= s) { b += DDIM - d; ++d; }
  *dd = d; *ff = d + (s - b);
}

// ---------------------------------------------------------------------------
// Kernel 1: bf16 B-matrix, FRAGMENT-MAJOR layout, + fused zeroing.
// For m-row m, slot s: group = m>>4;
//   hw_off = group*GRPHW + (s>>5)*512 + ((s>>3)&3)*128 + (m&15)*8 + (s&7)
// so a wave's B-load (lane = quad*16+lrow) at kstep kk is the contiguous 1KB
// block Bm + group*GRPHW + kk*512 + lane*8.
// ---------------------------------------------------------------------------
__global__ __launch_bounds__(256) void build_b_kernel(
    const float* __restrict__ gamma, const float* __restrict__ means,
    unsigned short* __restrict__ Bm, double* __restrict__ acc,
    unsigned int* __restrict__ mcnt, unsigned int* __restrict__ fcount) {
  __shared__ float G[DDIM][DDIM + 1];
  __shared__ float C[DDIM][DDIM + 1];
  __shared__ float bv[DDIM];
  __shared__ float cc;
  const int m = blockIdx.x;
  const int t = threadIdx.x;
  if (t < 16) acc[m * 16 + t] = 0.0;                 // 2048*16 = 32768 entries
  if (t == 16) mcnt[m] = 0u;
  if (m == 0 && t == 17) *fcount = 0u;
  const float* g = gamma + (size_t)m * DDIM * DDIM;
  for (int l = t; l < DDIM * DDIM; l += 256) G[l >> 5][l & 31] = g[l];
  __syncthreads();
  const float* mu = means + m * DDIM;
  for (int l = t; l < DDIM * DDIM; l += 256) {
    int d = l >> 5, f = l & 31;
    float c = 0.f;
#pragma unroll
    for (int e = 0; e < DDIM; ++e) c += G[d][e] * G[f][e];
    C[d][f] = c;
  }
  __syncthreads();
  if (t < DDIM) {
    float b = 0.f;
#pragma unroll
    for (int f = 0; f < DDIM; ++f) b += C[t][f] * mu[f];
    bv[t] = b;
  }
  __syncthreads();
  if (t == 0) {
    float c = 0.f;
#pragma unroll
    for (int d = 0; d < DDIM; ++d) c += bv[d] * mu[d];
    cc = c;
  }
  __syncthreads();
  unsigned short* bgrp = Bm + (size_t)(m >> 4) * GRPHW + (m & 15) * 8;
  for (int s = t; s < KSYM; s += 256) {
    float val;
    if (s < 528) {
      int d, f; slot_df(s, &d, &f);
      val = (d == f) ? C[d][d] : 2.f * C[d][f];
    } else if (s < 560) {
      val = -2.f * bv[s - 528];
    } else if (s == 560) {
      val = cc;
    } else if (s == 561) {
      unsigned int hi = to_bf16(cc);
      union { unsigned int u; float f; } xh; xh.u = hi << 16;
      val = cc - xh.f;
    } else {
      val = 0.f;
    }
    const int hw = (s >> 5) * 512 + ((s >> 3) & 3) * 128 + (s & 7);
    bgrp[hw] = (unsigned short)to_bf16(val);
  }
}

// ---------------------------------------------------------------------------
// Exact scalar path (fallback list only).
// ---------------------------------------------------------------------------
__device__ __noinline__ double survivor_contrib(
    int m, const float* __restrict__ gamma, const float* __restrict__ means,
    const float* __restrict__ weights, const float* __restrict__ xrow) {
  const float* mu = means + m * DDIM;
  float v[DDIM];
#pragma unroll
  for (int d = 0; d < DDIM; ++d) v[d] = xrow[d] - mu[d];
  const float* g = gamma + (size_t)m * DDIM * DDIM;
  float Dex = 0.f;
  for (int e = 0; e < DDIM; ++e) {
    float y = 0.f;
#pragma unroll
    for (int d = 0; d < DDIM; ++d) y += g[d * DDIM + e] * v[d];
    Dex += y * y;
  }
  float e2 = -Dex * 1.44269504088896340736f;
  float kf = floorf(e2);
  float mant = exp2f(e2 - kf);
  return ldexp((double)(weights[m] * mant), (int)kf);
}

// ---------------------------------------------------------------------------
// Kernel 2: bf16 MFMA screen. 512 threads (8 waves), ROWS=64 A-tile in
// 73.7 KB dynamic LDS -> 2 blocks/CU -> 4 waves/SIMD (128-unified budget,
// pinned by amdgpu_waves_per_eu(4,4); r21 proved the 64 arch + 64 acc split
// is spill-free). Per kstep per wave: 4 B-loads (coalesced 1KB lane-linear,
// 2-deep rotation) + 4 ds_read_b128 + 16 MFMA (acc[4][4]). A ds addresses:
// even/odd 32-bit LDS offsets per ti; kp*128 folds into ds immediates.
// Wave w sweeps m-quads ((g*8+w)+rot)&31, rot=blockIdx&31. Frag layout
// (m89/m97): A/B [row=lane&15][k=quad*8+j]; C/D col=lane&15, row=quad*4+reg.
// Survivors -> per-m buckets; overflow -> flat list.
// ---------------------------------------------------------------------------
__global__ __launch_bounds__(512)
__attribute__((amdgpu_waves_per_eu(4, 4)))
void screen_kernel(
    const float* __restrict__ x, const unsigned short* __restrict__ Bm,
    unsigned int* __restrict__ mcnt, unsigned short* __restrict__ mlist,
    unsigned int* __restrict__ flist, unsigned int* __restrict__ fcount) {
  extern __shared__ __align__(16) unsigned short As[];   // ROWS * KSYM
  const int t = threadIdx.x;
  const int i0 = blockIdx.x * ROWS;
  const int lane = t & 63, w = t >> 6;                   // w in [0,8)
  const int lrow = lane & 15, quad = lane >> 4;
  const int rot = blockIdx.x & 31;

  // ---- generate A tile into swizzled LDS: row r (64), chunk-eighth j (8) ----
  {
    const int r = t >> 3, j = t & 7;
    float v[DDIM];
#pragma unroll
    for (int q = 0; q < 8; ++q)
      *(floatx4*)&v[q * 4] = *(const floatx4*)(x + (size_t)(i0 + r) * DDIM + q * 4);
#pragma unroll
    for (int cc2 = 0; cc2 < 9; ++cc2) {
      const int c = j * 9 + cc2;                       // 16B chunk index 0..71
      unsigned int uu[4];
#pragma unroll
      for (int q = 0; q < 4; ++q) {
        const int s0 = c * 8 + q * 2;
        uu[q] = to_bf16(slot_val(v, s0)) | (to_bf16(slot_val(v, s0 + 1)) << 16);
      }
      const int cs = (c & ~7) | ((c & 7) ^ (r & 7));
      uint4 o; o.x = uu[0]; o.y = uu[1]; o.z = uu[2]; o.w = uu[3];
      *(uint4*)&As[r * KSYM + cs * 8] = o;
    }
  }
  __syncthreads();

  // ---- precompute per-ti A ds-read byte offsets (even/odd kstep) ----
  int pae[4], pao[4];
#pragma unroll
  for (int ti = 0; ti < 4; ++ti) {
    const int rr = ti * 16 + lrow;
    const int rowb = rr * (KSYM * 2);
    pae[ti] = rowb + 16 * (quad ^ (rr & 7));
    pao[ti] = rowb + 16 * ((4 | quad) ^ (rr & 7));
  }

#pragma unroll 1
  for (int g = 0; g < 4; ++g) {
    const int mq = ((g * 8 + w) + rot) & 31;
    const int m0 = mq * 64;
    // fragment-major B: group = m-quad's 4 groups of 16 rows; lane-linear.
    const unsigned short* bbm[4];
#pragma unroll
    for (int mj = 0; mj < 4; ++mj)
      bbm[mj] = Bm + (size_t)(mq * 4 + mj) * GRPHW + lane * 8;

    floatx4 acc[4][4] = {};                              // [ti][mj]
    short8 bfr[2][4];                                    // 2-deep B rotation
    // prologue: load kstep 0
#pragma unroll
    for (int mj = 0; mj < 4; ++mj)
      bfr[0][mj] = *(const short8*)(bbm[mj]);
#pragma unroll
    for (int kk = 0; kk < KSTEPS; ++kk) {
      // issue loads for kstep kk+1 into the other buffer
      if (kk + 1 < KSTEPS) {
#pragma unroll
        for (int mj = 0; mj < 4; ++mj)
          bfr[(kk + 1) & 1][mj] = *(const short8*)(bbm[mj] + (kk + 1) * 512);
      }
#pragma unroll
      for (int ti = 0; ti < 4; ++ti) {
        const int pa = ((kk & 1) ? pao[ti] : pae[ti]) + (kk >> 1) * 128;
        short8 a = *(const short8*)((const char*)As + pa);
#pragma unroll
        for (int mj = 0; mj < 4; ++mj)
          acc[ti][mj] = __builtin_amdgcn_mfma_f32_16x16x32_bf16(
              a, bfr[kk & 1][mj], acc[ti][mj], 0, 0, 0);
      }
    }

    // screen & emit survivors (rare) into per-m buckets
#pragma unroll
    for (int ti = 0; ti < 4; ++ti)
#pragma unroll
      for (int mj = 0; mj < 4; ++mj)
#pragma unroll
        for (int r = 0; r < 4; ++r) {
          float Dt = acc[ti][mj][r];
          if (Dt < SCREEN) {
            int gi = i0 + ti * 16 + quad * 4 + r;
            int gm = m0 + mj * 16 + lrow;
            unsigned int idx = atomicAdd(&mcnt[gm], 1u);
            if (idx < MCAP) {
              mlist[(size_t)gm * MCAP + idx] = (unsigned short)gi;
            } else {
              unsigned int fi = atomicAdd(fcount, 1u);
              if (fi < FCAP)
                flist[fi] = ((unsigned int)gi << 11) | (unsigned int)gm;
            }
          }
        }
  }
}

// ---------------------------------------------------------------------------
// Kernel 3: survivor processing (per-m buckets + fallback list).
// ---------------------------------------------------------------------------
__global__ __launch_bounds__(256) void survivor2_kernel(
    const unsigned int* __restrict__ mcnt, const unsigned short* __restrict__ mlist,
    const unsigned int* __restrict__ flist, const unsigned int* __restrict__ fcount,
    const float* __restrict__ x, const float* __restrict__ gamma,
    const float* __restrict__ means, const float* __restrict__ weights,
    double* __restrict__ acc_out) {
  const int blk = blockIdx.x;
  const int t = threadIdx.x;
  if (blk >= MM) {
    unsigned int total = *fcount;
    if (total > FCAP) total = FCAP;
    for (unsigned int idx = (blk - MM) * 256 + t; idx < total; idx += FBLK * 256) {
      unsigned int p = flist[idx];
      int gi = (int)(p >> 11), gm = (int)(p & 2047u);
      double c = survivor_contrib(gm, gamma, means, weights, x + (size_t)gi * DDIM);
      atomicAdd(&acc_out[gi], c);
    }
    return;
  }
  __shared__ float Gt[DDIM][DDIM + 1];
  __shared__ float mu[DDIM];
  const int m = blk;
  unsigned int cnt = mcnt[m];
  if (cnt > MCAP) cnt = MCAP;
  if (cnt == 0) return;
  const float* g = gamma + (size_t)m * DDIM * DDIM;
  for (int l = t; l < DDIM * DDIM; l += 256) Gt[l & 31][l >> 5] = g[l];
  if (t < DDIM) mu[t] = means[m * DDIM + t];
  __syncthreads();
  const float wm = weights[m];
  for (unsigned int s = t; s < cnt; s += 256) {
    int gi = mlist[(size_t)m * MCAP + s];
    float v[DDIM];
#pragma unroll
    for (int q = 0; q < 8; ++q) {
      floatx4 xv = *(const floatx4*)(x + (size_t)gi * DDIM + q * 4);
      v[q * 4 + 0] = xv.x - mu[q * 4 + 0];
      v[q * 4 + 1] = xv.y - mu[q * 4 + 1];
      v[q * 4 + 2] = xv.z - mu[q * 4 + 2];
      v[q * 4 + 3] = xv.w - mu[q * 4 + 3];
    }
    float Dex = 0.f;
#pragma unroll
    for (int e = 0; e < DDIM; ++e) {
      float y = 0.f;
#pragma unroll
      for (int d = 0; d < DDIM; ++d) y += Gt[e][d] * v[d];
      Dex += y * y;
    }
    float e2 = -Dex * 1.44269504088896340736f;
    float kf = floorf(e2);
    float mant = exp2f(e2 - kf);
    atomicAdd(&acc_out[gi], ldexp((double)(wm * mant), (int)kf));
  }
}

__global__ __launch_bounds__(256) void finalize_kernel(
    const double* __restrict__ acc, float* __restrict__ out) {
  int i = blockIdx.x * 256 + threadIdx.x;
  out[i] = (float)acc[i];
}

extern "C" void kernel_launch(void* const* d_in, const int* in_sizes, int n_in,
                              void* d_out, int out_size, void* d_ws, size_t ws_size,
                              hipStream_t stream) {
  (void)in_sizes; (void)n_in; (void)out_size;
  const float* x       = (const float*)d_in[0];   // [N][32]
  const float* gamma   = (const float*)d_in[1];   // [M][32][32]
  const float* means   = (const float*)d_in[2];   // [M][32]
  const float* weights = (const float*)d_in[3];   // [M]

  char* p = (char*)d_ws;
  double* acc          = (double*)p;            p += (size_t)NN * 8;
  unsigned int* fcount = (unsigned int*)p;      p += 16;
  unsigned int* mcnt   = (unsigned int*)p;      p += (size_t)MM * 4;
  unsigned short* mlist= (unsigned short*)p;    p += (size_t)MM * MCAP * 2;
  unsigned int* flist  = (unsigned int*)p;      p += (size_t)FCAP * 4;
  unsigned short* Bm   = (unsigned short*)p;    p += (size_t)MM * KSYM * 2;
  const size_t needed = (size_t)(p - (char*)d_ws);
  if (ws_size < needed) return;

  (void)hipFuncSetAttribute((const void*)screen_kernel,
                            hipFuncAttributeMaxDynamicSharedMemorySize,
                            ROWS * KSYM * 2);

  hipLaunchKernelGGL(build_b_kernel, dim3(MM), dim3(256), 0, stream,
                     gamma, means, Bm, acc, mcnt, fcount);
  hipLaunchKernelGGL(screen_kernel, dim3(NN / ROWS), dim3(512),
                     ROWS * KSYM * 2, stream,
                     x, Bm, mcnt, mlist, flist, fcount);
  hipLaunchKernelGGL(survivor2_kernel, dim3(MM + FBLK), dim3(256), 0, stream,
                     mcnt, mlist, flist, fcount, x, gamma, means, weights, acc);
  hipLaunchKernelGGL(finalize_kernel, dim3(NN / 256), dim3(256), 0, stream,
                     acc, (float*)d_out);
}

// Round 14
// 176.849 us; speedup vs baseline: 1.2778x; 1.2778x over previous
//
#include <hip/hip_runtime.h>
#include <math.h>

// RBF mixture: out[i] = sum_m w_m * exp(-(x_i-mu_m)^T C_m (x_i-mu_m)), C_m = G_m G_m^T
// N=32768, M=2048, D=32.
// Round 30: r29 with the A-gen scratch bug fixed (rule #20).
//  - r29's A-gen used runtime chunk index c=j*9+cc2 -> v[DFT.d[s]] became
//    dynamically-indexed -> v[32] allocated in SCRATCH (WRITE 20.5 MB,
//    VALUBusy 64%, screen 141us). NOT a register-budget failure.
//  - Fix: jj-branch trick (for jj if (j==jj)) makes all slot indices
//    compile-time -> v[32] in registers. Phase peaks: A-gen ~45 arch,
//    main loop ~60 arch + 64 AGPR acc = fits the 128-unified budget pinned
//    by amdgpu_waves_per_eu(4,4) at 2 blocks/CU (ROWS=64, 73.7KB LDS).
//  - Everything else identical to r29 (coalesced fragment-major B, 2-deep
//    rotation, SCREEN=104, other kernels verbatim).
// 4 dispatches total.

#define NN 32768
#define MM 2048
#define DDIM 32
#define KSYM 576           // 528 triangle + 32 cross + 2 const + 14 pad = 18*32
#define ROWS 64
#define KSTEPS 18
#define SCREEN 104.0f
#define MCAP 2048
#define FCAP 1000000
#define FBLK 64
#define GRPHW 9216         // halfwords per 16-m B group: 16*576

typedef __attribute__((ext_vector_type(8))) short short8;
typedef __attribute__((ext_vector_type(4))) float floatx4;

__device__ __forceinline__ unsigned int to_bf16(float f) {
  union { float f; unsigned int u; } x; x.f = f;
  return (x.u + 0x7fffu + ((x.u >> 16) & 1u)) >> 16;   // RNE, finite inputs only
}

struct DFTab { unsigned char d[528]; unsigned char f[528]; };
constexpr DFTab make_df() {
  DFTab t{};
  int s = 0;
  for (int d = 0; d < 32; ++d)
    for (int f = d; f < 32; ++f) {
      t.d[s] = (unsigned char)d; t.f[s] = (unsigned char)f; ++s;
    }
  return t;
}
constexpr DFTab DFT = make_df();

__device__ __forceinline__ float slot_val(const float* v, int s) {
  if (s < 528) return v[DFT.d[s]] * v[DFT.f[s]];
  if (s < 560) return v[s - 528];
  if (s < 562) return 1.f;
  return 0.f;
}

__device__ __forceinline__ void slot_df(int s, int* dd, int* ff) {
  int d = 0, b = 0;
  while (b + (DDIM - d) <= s) { b += DDIM - d; ++d; }
  *dd = d; *ff = d + (s - b);
}

// ---------------------------------------------------------------------------
// Kernel 1: bf16 B-matrix, FRAGMENT-MAJOR layout, + fused zeroing.
// For m-row m, slot s: group = m>>4;
//   hw_off = group*GRPHW + (s>>5)*512 + ((s>>3)&3)*128 + (m&15)*8 + (s&7)
// so a wave's B-load (lane = quad*16+lrow) at kstep kk is the contiguous 1KB
// block Bm + group*GRPHW + kk*512 + lane*8.
// ---------------------------------------------------------------------------
__global__ __launch_bounds__(256) void build_b_kernel(
    const float* __restrict__ gamma, const float* __restrict__ means,
    unsigned short* __restrict__ Bm, double* __restrict__ acc,
    unsigned int* __restrict__ mcnt, unsigned int* __restrict__ fcount) {
  __shared__ float G[DDIM][DDIM + 1];
  __shared__ float C[DDIM][DDIM + 1];
  __shared__ float bv[DDIM];
  __shared__ float cc;
  const int m = blockIdx.x;
  const int t = threadIdx.x;
  if (t < 16) acc[m * 16 + t] = 0.0;                 // 2048*16 = 32768 entries
  if (t == 16) mcnt[m] = 0u;
  if (m == 0 && t == 17) *fcount = 0u;
  const float* g = gamma + (size_t)m * DDIM * DDIM;
  for (int l = t; l < DDIM * DDIM; l += 256) G[l >> 5][l & 31] = g[l];
  __syncthreads();
  const float* mu = means + m * DDIM;
  for (int l = t; l < DDIM * DDIM; l += 256) {
    int d = l >> 5, f = l & 31;
    float c = 0.f;
#pragma unroll
    for (int e = 0; e < DDIM; ++e) c += G[d][e] * G[f][e];
    C[d][f] = c;
  }
  __syncthreads();
  if (t < DDIM) {
    float b = 0.f;
#pragma unroll
    for (int f = 0; f < DDIM; ++f) b += C[t][f] * mu[f];
    bv[t] = b;
  }
  __syncthreads();
  if (t == 0) {
    float c = 0.f;
#pragma unroll
    for (int d = 0; d < DDIM; ++d) c += bv[d] * mu[d];
    cc = c;
  }
  __syncthreads();
  unsigned short* bgrp = Bm + (size_t)(m >> 4) * GRPHW + (m & 15) * 8;
  for (int s = t; s < KSYM; s += 256) {
    float val;
    if (s < 528) {
      int d, f; slot_df(s, &d, &f);
      val = (d == f) ? C[d][d] : 2.f * C[d][f];
    } else if (s < 560) {
      val = -2.f * bv[s - 528];
    } else if (s == 560) {
      val = cc;
    } else if (s == 561) {
      unsigned int hi = to_bf16(cc);
      union { unsigned int u; float f; } xh; xh.u = hi << 16;
      val = cc - xh.f;
    } else {
      val = 0.f;
    }
    const int hw = (s >> 5) * 512 + ((s >> 3) & 3) * 128 + (s & 7);
    bgrp[hw] = (unsigned short)to_bf16(val);
  }
}

// ---------------------------------------------------------------------------
// Exact scalar path (fallback list only).
// ---------------------------------------------------------------------------
__device__ __noinline__ double survivor_contrib(
    int m, const float* __restrict__ gamma, const float* __restrict__ means,
    const float* __restrict__ weights, const float* __restrict__ xrow) {
  const float* mu = means + m * DDIM;
  float v[DDIM];
#pragma unroll
  for (int d = 0; d < DDIM; ++d) v[d] = xrow[d] - mu[d];
  const float* g = gamma + (size_t)m * DDIM * DDIM;
  float Dex = 0.f;
  for (int e = 0; e < DDIM; ++e) {
    float y = 0.f;
#pragma unroll
    for (int d = 0; d < DDIM; ++d) y += g[d * DDIM + e] * v[d];
    Dex += y * y;
  }
  float e2 = -Dex * 1.44269504088896340736f;
  float kf = floorf(e2);
  float mant = exp2f(e2 - kf);
  return ldexp((double)(weights[m] * mant), (int)kf);
}

// ---------------------------------------------------------------------------
// Kernel 2: bf16 MFMA screen. 512 threads (8 waves), ROWS=64 A-tile in
// 73.7 KB dynamic LDS -> 2 blocks/CU -> 4 waves/SIMD (128-unified budget
// pinned by amdgpu_waves_per_eu(4,4): 64 arch + 64 AGPR acc). A-gen uses
// the jj-branch trick so all slot indices are COMPILE-TIME -> v[32] stays
// in registers (r29 bug: runtime c -> v in scratch). Per kstep per wave:
// 4 B-loads (coalesced 1KB lane-linear, 2-deep rotation) + 4 ds_read_b128
// + 16 MFMA (acc[4][4]). A ds addresses: even/odd 32-bit LDS offsets per
// ti; kp*128 folds into ds immediates. Wave w sweeps m-quads
// ((g*8+w)+rot)&31, rot=blockIdx&31. Frag layout (m89/m97): A/B
// [row=lane&15][k=quad*8+j]; C/D col=lane&15, row=quad*4+reg.
// Survivors -> per-m buckets; overflow -> flat list.
// ---------------------------------------------------------------------------
__global__ __launch_bounds__(512)
__attribute__((amdgpu_waves_per_eu(4, 4)))
void screen_kernel(
    const float* __restrict__ x, const unsigned short* __restrict__ Bm,
    unsigned int* __restrict__ mcnt, unsigned short* __restrict__ mlist,
    unsigned int* __restrict__ flist, unsigned int* __restrict__ fcount) {
  extern __shared__ __align__(16) unsigned short As[];   // ROWS * KSYM
  const int t = threadIdx.x;
  const int i0 = blockIdx.x * ROWS;
  const int lane = t & 63, w = t >> 6;                   // w in [0,8)
  const int lrow = lane & 15, quad = lane >> 4;
  const int rot = blockIdx.x & 31;

  // ---- generate A tile into swizzled LDS: row r (64), chunk-eighth j (8).
  //      jj-branch keeps chunk indices compile-time (v[] stays in regs). ----
  {
    const int r = t >> 3, j = t & 7;
    float v[DDIM];
#pragma unroll
    for (int q = 0; q < 8; ++q)
      *(floatx4*)&v[q * 4] = *(const floatx4*)(x + (size_t)(i0 + r) * DDIM + q * 4);
#pragma unroll
    for (int jj = 0; jj < 8; ++jj) {
      if (j == jj) {
#pragma unroll
        for (int cc2 = 0; cc2 < 9; ++cc2) {
          const int c = jj * 9 + cc2;                  // compile-time 0..71
          unsigned int uu[4];
#pragma unroll
          for (int q = 0; q < 4; ++q) {
            const int s0 = c * 8 + q * 2;
            uu[q] = to_bf16(slot_val(v, s0)) | (to_bf16(slot_val(v, s0 + 1)) << 16);
          }
          const int cs = (c & ~7) | ((c & 7) ^ (r & 7));
          uint4 o; o.x = uu[0]; o.y = uu[1]; o.z = uu[2]; o.w = uu[3];
          *(uint4*)&As[r * KSYM + cs * 8] = o;
        }
      }
    }
  }
  __syncthreads();

  // ---- precompute per-ti A ds-read byte offsets (even kstep; odd = ^64) ----
  int pae[4];
#pragma unroll
  for (int ti = 0; ti < 4; ++ti) {
    const int rr = ti * 16 + lrow;
    pae[ti] = rr * (KSYM * 2) + 16 * (quad ^ (rr & 7));
  }

#pragma unroll 1
  for (int g = 0; g < 4; ++g) {
    const int mq = ((g * 8 + w) + rot) & 31;
    const int m0 = mq * 64;
    // fragment-major B: group = m-quad's 4 groups of 16 rows; lane-linear.
    const unsigned short* bbm[4];
#pragma unroll
    for (int mj = 0; mj < 4; ++mj)
      bbm[mj] = Bm + (size_t)(mq * 4 + mj) * GRPHW + lane * 8;

    floatx4 acc[4][4] = {};                              // [ti][mj]
    short8 bfr[2][4];                                    // 2-deep B rotation
    // prologue: load kstep 0
#pragma unroll
    for (int mj = 0; mj < 4; ++mj)
      bfr[0][mj] = *(const short8*)(bbm[mj]);
#pragma unroll
    for (int kk = 0; kk < KSTEPS; ++kk) {
      // issue loads for kstep kk+1 into the other buffer
      if (kk + 1 < KSTEPS) {
#pragma unroll
        for (int mj = 0; mj < 4; ++mj)
          bfr[(kk + 1) & 1][mj] = *(const short8*)(bbm[mj] + (kk + 1) * 512);
      }
#pragma unroll
      for (int ti = 0; ti < 4; ++ti) {
        const int pa = (pae[ti] ^ ((kk & 1) << 6)) + (kk >> 1) * 128;
        short8 a = *(const short8*)((const char*)As + pa);
#pragma unroll
        for (int mj = 0; mj < 4; ++mj)
          acc[ti][mj] = __builtin_amdgcn_mfma_f32_16x16x32_bf16(
              a, bfr[kk & 1][mj], acc[ti][mj], 0, 0, 0);
      }
    }

    // screen & emit survivors (rare) into per-m buckets
#pragma unroll
    for (int ti = 0; ti < 4; ++ti)
#pragma unroll
      for (int mj = 0; mj < 4; ++mj)
#pragma unroll
        for (int r = 0; r < 4; ++r) {
          float Dt = acc[ti][mj][r];
          if (Dt < SCREEN) {
            int gi = i0 + ti * 16 + quad * 4 + r;
            int gm = m0 + mj * 16 + lrow;
            unsigned int idx = atomicAdd(&mcnt[gm], 1u);
            if (idx < MCAP) {
              mlist[(size_t)gm * MCAP + idx] = (unsigned short)gi;
            } else {
              unsigned int fi = atomicAdd(fcount, 1u);
              if (fi < FCAP)
                flist[fi] = ((unsigned int)gi << 11) | (unsigned int)gm;
            }
          }
        }
  }
}

// ---------------------------------------------------------------------------
// Kernel 3: survivor processing (per-m buckets + fallback list).
// ---------------------------------------------------------------------------
__global__ __launch_bounds__(256) void survivor2_kernel(
    const unsigned int* __restrict__ mcnt, const unsigned short* __restrict__ mlist,
    const unsigned int* __restrict__ flist, const unsigned int* __restrict__ fcount,
    const float* __restrict__ x, const float* __restrict__ gamma,
    const float* __restrict__ means, const float* __restrict__ weights,
    double* __restrict__ acc_out) {
  const int blk = blockIdx.x;
  const int t = threadIdx.x;
  if (blk >= MM) {
    unsigned int total = *fcount;
    if (total > FCAP) total = FCAP;
    for (unsigned int idx = (blk - MM) * 256 + t; idx < total; idx += FBLK * 256) {
      unsigned int p = flist[idx];
      int gi = (int)(p >> 11), gm = (int)(p & 2047u);
      double c = survivor_contrib(gm, gamma, means, weights, x + (size_t)gi * DDIM);
      atomicAdd(&acc_out[gi], c);
    }
    return;
  }
  __shared__ float Gt[DDIM][DDIM + 1];
  __shared__ float mu[DDIM];
  const int m = blk;
  unsigned int cnt = mcnt[m];
  if (cnt > MCAP) cnt = MCAP;
  if (cnt == 0) return;
  const float* g = gamma + (size_t)m * DDIM * DDIM;
  for (int l = t; l < DDIM * DDIM; l += 256) Gt[l & 31][l >> 5] = g[l];
  if (t < DDIM) mu[t] = means[m * DDIM + t];
  __syncthreads();
  const float wm = weights[m];
  for (unsigned int s = t; s < cnt; s += 256) {
    int gi = mlist[(size_t)m * MCAP + s];
    float v[DDIM];
#pragma unroll
    for (int q = 0; q < 8; ++q) {
      floatx4 xv = *(const floatx4*)(x + (size_t)gi * DDIM + q * 4);
      v[q * 4 + 0] = xv.x - mu[q * 4 + 0];
      v[q * 4 + 1] = xv.y - mu[q * 4 + 1];
      v[q * 4 + 2] = xv.z - mu[q * 4 + 2];
      v[q * 4 + 3] = xv.w - mu[q * 4 + 3];
    }
    float Dex = 0.f;
#pragma unroll
    for (int e = 0; e < DDIM; ++e) {
      float y = 0.f;
#pragma unroll
      for (int d = 0; d < DDIM; ++d) y += Gt[e][d] * v[d];
      Dex += y * y;
    }
    float e2 = -Dex * 1.44269504088896340736f;
    float kf = floorf(e2);
    float mant = exp2f(e2 - kf);
    atomicAdd(&acc_out[gi], ldexp((double)(wm * mant), (int)kf));
  }
}

__global__ __launch_bounds__(256) void finalize_kernel(
    const double* __restrict__ acc, float* __restrict__ out) {
  int i = blockIdx.x * 256 + threadIdx.x;
  out[i] = (float)acc[i];
}

extern "C" void kernel_launch(void* const* d_in, const int* in_sizes, int n_in,
                              void* d_out, int out_size, void* d_ws, size_t ws_size,
                              hipStream_t stream) {
  (void)in_sizes; (void)n_in; (void)out_size;
  const float* x       = (const float*)d_in[0];   // [N][32]
  const float* gamma   = (const float*)d_in[1];   // [M][32][32]
  const float* means   = (const float*)d_in[2];   // [M][32]
  const float* weights = (const float*)d_in[3];   // [M]

  char* p = (char*)d_ws;
  double* acc          = (double*)p;            p += (size_t)NN * 8;
  unsigned int* fcount = (unsigned int*)p;      p += 16;
  unsigned int* mcnt   = (unsigned int*)p;      p += (size_t)MM * 4;
  unsigned short* mlist= (unsigned short*)p;    p += (size_t)MM * MCAP * 2;
  unsigned int* flist  = (unsigned int*)p;      p += (size_t)FCAP * 4;
  unsigned short* Bm   = (unsigned short*)p;    p += (size_t)MM * KSYM * 2;
  const size_t needed = (size_t)(p - (char*)d_ws);
  if (ws_size < needed) return;

  (void)hipFuncSetAttribute((const void*)screen_kernel,
                            hipFuncAttributeMaxDynamicSharedMemorySize,
                            ROWS * KSYM * 2);

  hipLaunchKernelGGL(build_b_kernel, dim3(MM), dim3(256), 0, stream,
                     gamma, means, Bm, acc, mcnt, fcount);
  hipLaunchKernelGGL(screen_kernel, dim3(NN / ROWS), dim3(512),
                     ROWS * KSYM * 2, stream,
                     x, Bm, mcnt, mlist, flist, fcount);
  hipLaunchKernelGGL(survivor2_kernel, dim3(MM + FBLK), dim3(256), 0, stream,
                     mcnt, mlist, flist, fcount, x, gamma, means, weights, acc);
  hipLaunchKernelGGL(finalize_kernel, dim3(NN / 256), dim3(256), 0, stream,
                     acc, (float*)d_out);
}

// Round 15
// 160.781 us; speedup vs baseline: 1.4055x; 1.0999x over previous
//
#include <hip/hip_runtime.h>
#include <math.h>

// RBF mixture: out[i] = sum_m w_m * exp(-(x_i-mu_m)^T C_m (x_i-mu_m)), C_m = G_m G_m^T
// N=32768, M=2048, D=32.
// Round 31: revert to r27 (best verified, 163.7us) + setprio A/B.
//  - r28/r29/r30 verdict: 4 waves/SIMD is register-infeasible (acc >= 64 AGPR
//    leaves < needed arch regs at the 128-unified cap; spill every time).
//    ROWS=128 / 2 waves/SIMD / 256-reg budget is the right operating point.
//  - Single change vs r27: s_setprio(1/0) around each 32-MFMA cluster.
//    Main loop is barrier-free, waves phase-diverse (independent m-streams)
//    -> the regime where setprio measured +4-7% (not lockstep-GEMM null).
//  - SCREEN=104 (r27-verified), coalesced fragment-major B (r26), 3-deep
//    B rotation, other kernels verbatim.
// 4 dispatches total.

#define NN 32768
#define MM 2048
#define DDIM 32
#define KSYM 576           // 528 triangle + 32 cross + 2 const + 14 pad = 18*32
#define ROWS 128
#define KSTEPS 18
#define SCREEN 104.0f
#define MCAP 2048
#define FCAP 1000000
#define FBLK 64
#define GRPHW 9216         // halfwords per 16-m B group: 16*576

typedef __attribute__((ext_vector_type(8))) short short8;
typedef __attribute__((ext_vector_type(4))) float floatx4;

__device__ __forceinline__ unsigned int to_bf16(float f) {
  union { float f; unsigned int u; } x; x.f = f;
  return (x.u + 0x7fffu + ((x.u >> 16) & 1u)) >> 16;   // RNE, finite inputs only
}

struct DFTab { unsigned char d[528]; unsigned char f[528]; };
constexpr DFTab make_df() {
  DFTab t{};
  int s = 0;
  for (int d = 0; d < 32; ++d)
    for (int f = d; f < 32; ++f) {
      t.d[s] = (unsigned char)d; t.f[s] = (unsigned char)f; ++s;
    }
  return t;
}
constexpr DFTab DFT = make_df();

__device__ __forceinline__ float slot_val(const float* v, int s) {
  if (s < 528) return v[DFT.d[s]] * v[DFT.f[s]];
  if (s < 560) return v[s - 528];
  if (s < 562) return 1.f;
  return 0.f;
}

__device__ __forceinline__ void slot_df(int s, int* dd, int* ff) {
  int d = 0, b = 0;
  while (b + (DDIM - d) <= s) { b += DDIM - d; ++d; }
  *dd = d; *ff = d + (s - b);
}

// ---------------------------------------------------------------------------
// Kernel 1: bf16 B-matrix, FRAGMENT-MAJOR layout, + fused zeroing.
// For m-row m, slot s: group = m>>4;
//   hw_off = group*GRPHW + (s>>5)*512 + ((s>>3)&3)*128 + (m&15)*8 + (s&7)
// so a wave's B-load (lane = quad*16+lrow) at kstep kk is the contiguous 1KB
// block Bm + group*GRPHW + kk*512 + lane*8.
// ---------------------------------------------------------------------------
__global__ __launch_bounds__(256) void build_b_kernel(
    const float* __restrict__ gamma, const float* __restrict__ means,
    unsigned short* __restrict__ Bm, double* __restrict__ acc,
    unsigned int* __restrict__ mcnt, unsigned int* __restrict__ fcount) {
  __shared__ float G[DDIM][DDIM + 1];
  __shared__ float C[DDIM][DDIM + 1];
  __shared__ float bv[DDIM];
  __shared__ float cc;
  const int m = blockIdx.x;
  const int t = threadIdx.x;
  if (t < 16) acc[m * 16 + t] = 0.0;                 // 2048*16 = 32768 entries
  if (t == 16) mcnt[m] = 0u;
  if (m == 0 && t == 17) *fcount = 0u;
  const float* g = gamma + (size_t)m * DDIM * DDIM;
  for (int l = t; l < DDIM * DDIM; l += 256) G[l >> 5][l & 31] = g[l];
  __syncthreads();
  const float* mu = means + m * DDIM;
  for (int l = t; l < DDIM * DDIM; l += 256) {
    int d = l >> 5, f = l & 31;
    float c = 0.f;
#pragma unroll
    for (int e = 0; e < DDIM; ++e) c += G[d][e] * G[f][e];
    C[d][f] = c;
  }
  __syncthreads();
  if (t < DDIM) {
    float b = 0.f;
#pragma unroll
    for (int f = 0; f < DDIM; ++f) b += C[t][f] * mu[f];
    bv[t] = b;
  }
  __syncthreads();
  if (t == 0) {
    float c = 0.f;
#pragma unroll
    for (int d = 0; d < DDIM; ++d) c += bv[d] * mu[d];
    cc = c;
  }
  __syncthreads();
  unsigned short* bgrp = Bm + (size_t)(m >> 4) * GRPHW + (m & 15) * 8;
  for (int s = t; s < KSYM; s += 256) {
    float val;
    if (s < 528) {
      int d, f; slot_df(s, &d, &f);
      val = (d == f) ? C[d][d] : 2.f * C[d][f];
    } else if (s < 560) {
      val = -2.f * bv[s - 528];
    } else if (s == 560) {
      val = cc;
    } else if (s == 561) {
      unsigned int hi = to_bf16(cc);
      union { unsigned int u; float f; } xh; xh.u = hi << 16;
      val = cc - xh.f;
    } else {
      val = 0.f;
    }
    const int hw = (s >> 5) * 512 + ((s >> 3) & 3) * 128 + (s & 7);
    bgrp[hw] = (unsigned short)to_bf16(val);
  }
}

// ---------------------------------------------------------------------------
// Exact scalar path (fallback list only).
// ---------------------------------------------------------------------------
__device__ __noinline__ double survivor_contrib(
    int m, const float* __restrict__ gamma, const float* __restrict__ means,
    const float* __restrict__ weights, const float* __restrict__ xrow) {
  const float* mu = means + m * DDIM;
  float v[DDIM];
#pragma unroll
  for (int d = 0; d < DDIM; ++d) v[d] = xrow[d] - mu[d];
  const float* g = gamma + (size_t)m * DDIM * DDIM;
  float Dex = 0.f;
  for (int e = 0; e < DDIM; ++e) {
    float y = 0.f;
#pragma unroll
    for (int d = 0; d < DDIM; ++d) y += g[d * DDIM + e] * v[d];
    Dex += y * y;
  }
  float e2 = -Dex * 1.44269504088896340736f;
  float kf = floorf(e2);
  float mant = exp2f(e2 - kf);
  return ldexp((double)(weights[m] * mant), (int)kf);
}

// ---------------------------------------------------------------------------
// Kernel 2: bf16 MFMA screen. 512 threads (8 waves, 2/SIMD, 256-reg budget),
// 128-row A-tile generated in-kernel into 147 KB dynamic LDS (XOR chunk
// swizzle; 0 conflicts r3-r30). 1 block/CU. Main loop per kstep: 4 B-loads
// (coalesced 1KB lane-linear from fragment-major Bm; kstep k+2 via 3-buffer
// rotation) + 8 ds_read_b128 + 32 MFMA wrapped in s_setprio(1/0) (waves are
// phase-diverse; attn-like regime). A ds addresses: even/odd 32-bit LDS
// offsets per ti; kp*128 folds into ds immediates. Wave w sweeps m-quads
// ((g*8+w)+rot)&31, rot=blockIdx&31. Frag layout (m89/m97): A/B
// [row=lane&15][k=quad*8+j]; C/D col=lane&15, row=quad*4+reg.
// Survivors -> per-m buckets; overflow -> flat list.
// ---------------------------------------------------------------------------
__global__ __launch_bounds__(512, 1) void screen_kernel(
    const float* __restrict__ x, const unsigned short* __restrict__ Bm,
    unsigned int* __restrict__ mcnt, unsigned short* __restrict__ mlist,
    unsigned int* __restrict__ flist, unsigned int* __restrict__ fcount) {
  extern __shared__ __align__(16) unsigned short As[];   // ROWS * KSYM
  const int t = threadIdx.x;
  const int i0 = blockIdx.x * ROWS;
  const int lane = t & 63, w = t >> 6;                   // w in [0,8)
  const int lrow = lane & 15, quad = lane >> 4;
  const int rot = blockIdx.x & 31;

  // ---- generate A tile into swizzled LDS: row r (128), chunk-quarter j (4) ----
  {
    const int r = t >> 2, j = t & 3;
    float v[DDIM];
#pragma unroll
    for (int q = 0; q < 8; ++q)
      *(floatx4*)&v[q * 4] = *(const floatx4*)(x + (size_t)(i0 + r) * DDIM + q * 4);
#pragma unroll
    for (int jj = 0; jj < 4; ++jj) {
      if (j == jj) {
#pragma unroll
        for (int cc2 = 0; cc2 < 18; ++cc2) {
          const int c = jj * 18 + cc2;                   // 16B chunk index 0..71
          unsigned int uu[4];
#pragma unroll
          for (int q = 0; q < 4; ++q) {
            const int s0 = c * 8 + q * 2;
            uu[q] = to_bf16(slot_val(v, s0)) | (to_bf16(slot_val(v, s0 + 1)) << 16);
          }
          const int cs = (c & ~7) | ((c & 7) ^ (r & 7));
          uint4 o; o.x = uu[0]; o.y = uu[1]; o.z = uu[2]; o.w = uu[3];
          *(uint4*)&As[r * KSYM + cs * 8] = o;
        }
      }
    }
  }
  __syncthreads();

  // ---- precompute per-ti A ds-read byte offsets (even/odd kstep) ----
  int pae[8], pao[8];
#pragma unroll
  for (int ti = 0; ti < 8; ++ti) {
    const int rr = ti * 16 + lrow;
    const int rowb = rr * (KSYM * 2);
    pae[ti] = rowb + 16 * (quad ^ (rr & 7));
    pao[ti] = rowb + 16 * ((4 | quad) ^ (rr & 7));
  }

#pragma unroll 1
  for (int g = 0; g < 4; ++g) {
    const int mq = ((g * 8 + w) + rot) & 31;
    const int m0 = mq * 64;
    // fragment-major B: group = m-quad's 4 groups of 16 rows; lane-linear.
    const unsigned short* bbm[4];
#pragma unroll
    for (int mj = 0; mj < 4; ++mj)
      bbm[mj] = Bm + (size_t)(mq * 4 + mj) * GRPHW + lane * 8;

    floatx4 acc[8][4] = {};                              // [ti][mj]
    short8 bfr[3][4];                                    // 3-deep B rotation
    // prologue: load ksteps 0 and 1
#pragma unroll
    for (int p = 0; p < 2; ++p) {
#pragma unroll
      for (int mj = 0; mj < 4; ++mj)
        bfr[p][mj] = *(const short8*)(bbm[mj] + p * 512);
    }
#pragma unroll
    for (int kk = 0; kk < KSTEPS; ++kk) {
      // issue loads for kstep kk+2 into the buffer freed two steps ago
      if (kk + 2 < KSTEPS) {
#pragma unroll
        for (int mj = 0; mj < 4; ++mj)
          bfr[(kk + 2) % 3][mj] = *(const short8*)(bbm[mj] + (kk + 2) * 512);
      }
      __builtin_amdgcn_s_setprio(1);
#pragma unroll
      for (int ti = 0; ti < 8; ++ti) {
        const int pa = ((kk & 1) ? pao[ti] : pae[ti]) + (kk >> 1) * 128;
        short8 a = *(const short8*)((const char*)As + pa);
#pragma unroll
        for (int mj = 0; mj < 4; ++mj)
          acc[ti][mj] = __builtin_amdgcn_mfma_f32_16x16x32_bf16(
              a, bfr[kk % 3][mj], acc[ti][mj], 0, 0, 0);
      }
      __builtin_amdgcn_s_setprio(0);
    }

    // screen & emit survivors (rare) into per-m buckets
#pragma unroll
    for (int ti = 0; ti < 8; ++ti)
#pragma unroll
      for (int mj = 0; mj < 4; ++mj)
#pragma unroll
        for (int r = 0; r < 4; ++r) {
          float Dt = acc[ti][mj][r];
          if (Dt < SCREEN) {
            int gi = i0 + ti * 16 + quad * 4 + r;
            int gm = m0 + mj * 16 + lrow;
            unsigned int idx = atomicAdd(&mcnt[gm], 1u);
            if (idx < MCAP) {
              mlist[(size_t)gm * MCAP + idx] = (unsigned short)gi;
            } else {
              unsigned int fi = atomicAdd(fcount, 1u);
              if (fi < FCAP)
                flist[fi] = ((unsigned int)gi << 11) | (unsigned int)gm;
            }
          }
        }
  }
}

// ---------------------------------------------------------------------------
// Kernel 3: survivor processing (per-m buckets + fallback list).
// ---------------------------------------------------------------------------
__global__ __launch_bounds__(256) void survivor2_kernel(
    const unsigned int* __restrict__ mcnt, const unsigned short* __restrict__ mlist,
    const unsigned int* __restrict__ flist, const unsigned int* __restrict__ fcount,
    const float* __restrict__ x, const float* __restrict__ gamma,
    const float* __restrict__ means, const float* __restrict__ weights,
    double* __restrict__ acc_out) {
  const int blk = blockIdx.x;
  const int t = threadIdx.x;
  if (blk >= MM) {
    unsigned int total = *fcount;
    if (total > FCAP) total = FCAP;
    for (unsigned int idx = (blk - MM) * 256 + t; idx < total; idx += FBLK * 256) {
      unsigned int p = flist[idx];
      int gi = (int)(p >> 11), gm = (int)(p & 2047u);
      double c = survivor_contrib(gm, gamma, means, weights, x + (size_t)gi * DDIM);
      atomicAdd(&acc_out[gi], c);
    }
    return;
  }
  __shared__ float Gt[DDIM][DDIM + 1];
  __shared__ float mu[DDIM];
  const int m = blk;
  unsigned int cnt = mcnt[m];
  if (cnt > MCAP) cnt = MCAP;
  if (cnt == 0) return;
  const float* g = gamma + (size_t)m * DDIM * DDIM;
  for (int l = t; l < DDIM * DDIM; l += 256) Gt[l & 31][l >> 5] = g[l];
  if (t < DDIM) mu[t] = means[m * DDIM + t];
  __syncthreads();
  const float wm = weights[m];
  for (unsigned int s = t; s < cnt; s += 256) {
    int gi = mlist[(size_t)m * MCAP + s];
    float v[DDIM];
#pragma unroll
    for (int q = 0; q < 8; ++q) {
      floatx4 xv = *(const floatx4*)(x + (size_t)gi * DDIM + q * 4);
      v[q * 4 + 0] = xv.x - mu[q * 4 + 0];
      v[q * 4 + 1] = xv.y - mu[q * 4 + 1];
      v[q * 4 + 2] = xv.z - mu[q * 4 + 2];
      v[q * 4 + 3] = xv.w - mu[q * 4 + 3];
    }
    float Dex = 0.f;
#pragma unroll
    for (int e = 0; e < DDIM; ++e) {
      float y = 0.f;
#pragma unroll
      for (int d = 0; d < DDIM; ++d) y += Gt[e][d] * v[d];
      Dex += y * y;
    }
    float e2 = -Dex * 1.44269504088896340736f;
    float kf = floorf(e2);
    float mant = exp2f(e2 - kf);
    atomicAdd(&acc_out[gi], ldexp((double)(wm * mant), (int)kf));
  }
}

__global__ __launch_bounds__(256) void finalize_kernel(
    const double* __restrict__ acc, float* __restrict__ out) {
  int i = blockIdx.x * 256 + threadIdx.x;
  out[i] = (float)acc[i];
}

extern "C" void kernel_launch(void* const* d_in, const int* in_sizes, int n_in,
                              void* d_out, int out_size, void* d_ws, size_t ws_size,
                              hipStream_t stream) {
  (void)in_sizes; (void)n_in; (void)out_size;
  const float* x       = (const float*)d_in[0];   // [N][32]
  const float* gamma   = (const float*)d_in[1];   // [M][32][32]
  const float* means   = (const float*)d_in[2];   // [M][32]
  const float* weights = (const float*)d_in[3];   // [M]

  char* p = (char*)d_ws;
  double* acc          = (double*)p;            p += (size_t)NN * 8;
  unsigned int* fcount = (unsigned int*)p;      p += 16;
  unsigned int* mcnt   = (unsigned int*)p;      p += (size_t)MM * 4;
  unsigned short* mlist= (unsigned short*)p;    p += (size_t)MM * MCAP * 2;
  unsigned int* flist  = (unsigned int*)p;      p += (size_t)FCAP * 4;
  unsigned short* Bm   = (unsigned short*)p;    p += (size_t)MM * KSYM * 2;
  const size_t needed = (size_t)(p - (char*)d_ws);
  if (ws_size < needed) return;

  (void)hipFuncSetAttribute((const void*)screen_kernel,
                            hipFuncAttributeMaxDynamicSharedMemorySize,
                            ROWS * KSYM * 2);

  hipLaunchKernelGGL(build_b_kernel, dim3(MM), dim3(256), 0, stream,
                     gamma, means, Bm, acc, mcnt, fcount);
  hipLaunchKernelGGL(screen_kernel, dim3(NN / ROWS), dim3(512),
                     ROWS * KSYM * 2, stream,
                     x, Bm, mcnt, mlist, flist, fcount);
  hipLaunchKernelGGL(survivor2_kernel, dim3(MM + FBLK), dim3(256), 0, stream,
                     mcnt, mlist, flist, fcount, x, gamma, means, weights, acc);
  hipLaunchKernelGGL(finalize_kernel, dim3(NN / 256), dim3(256), 0, stream,
                     acc, (float*)d_out);
}